// Round 5
// baseline (388.162 us; speedup 1.0000x reference)
//
#include <hip/hip_runtime.h>
#include <hip/hip_bf16.h>

#define NN 100000
#define NE 1600000
#define NBK 196          // buckets of 512 nodes: ceil(100000/512)

typedef __attribute__((ext_vector_type(8))) short bf16x8;
typedef __attribute__((ext_vector_type(4))) float f32x4;

__device__ __forceinline__ unsigned short f2bf(float x) {
    unsigned u = __float_as_uint(x);
    return (unsigned short)((u + 0x7fffu + ((u >> 16) & 1u)) >> 16);
}
__device__ __forceinline__ float bflo(unsigned v) { return __uint_as_float(v << 16); }
__device__ __forceinline__ float bfhi(unsigned v) { return __uint_as_float(v & 0xffff0000u); }

// ---------------- cast x (f32) -> bf16 ----------------
__global__ void cast_x(const float* __restrict__ x, unsigned short* __restrict__ h, int n) {
    int i = (blockIdx.x * blockDim.x + threadIdx.x) * 4;
    if (i >= n) return;
    float4 v = *(const float4*)(x + i);
    unsigned out0 = ((unsigned)f2bf(v.y) << 16) | f2bf(v.x);
    unsigned out1 = ((unsigned)f2bf(v.w) << 16) | f2bf(v.z);
    *(uint2*)(h + i) = make_uint2(out0, out1);
}

// ---------------- bucket histogram (196 buckets, LDS-first) ----------------
__global__ __launch_bounds__(256) void hist_buck(const int* __restrict__ dst, int* __restrict__ bhist) {
    __shared__ int h[NBK];
    int t = threadIdx.x;
    if (t < NBK) h[t] = 0;
    __syncthreads();
    int base = blockIdx.x * 4096;
#pragma unroll
    for (int i = 0; i < 16; ++i) {
        int e = base + t + i * 256;
        if (e < NE) atomicAdd(&h[dst[e] >> 9], 1);
    }
    __syncthreads();
    if (t < NBK && h[t]) atomicAdd(&bhist[t], h[t]);
}

// ------- scan buckets -> bbase (exclusive, bbase[NBK]=NE) + init gcur + row_ptr[NN] -------
__global__ void scan_buck(const int* __restrict__ bhist, int* __restrict__ bbase,
                          int* __restrict__ gcur, int* __restrict__ row_ptr) {
    __shared__ int s[256];
    int t = threadIdx.x;
    int v = (t < NBK) ? bhist[t] : 0;
    s[t] = v;
    __syncthreads();
    for (int off = 1; off < 256; off <<= 1) {
        int u = (t >= off) ? s[t - off] : 0;
        __syncthreads();
        s[t] += u;
        __syncthreads();
    }
    int ex = s[t] - v;
    if (t <= NBK) bbase[t] = ex;          // bbase[NBK] == NE
    if (t < NBK) gcur[t * 16] = ex;
    if (t == 0) row_ptr[NN] = NE;
}

// ------- block-local counting sort; contiguous runs per (block,bucket) -------
__global__ __launch_bounds__(256) void sort_scatter(const int* __restrict__ src,
                                                    const int* __restrict__ dst,
                                                    int* __restrict__ gcur,
                                                    unsigned* __restrict__ pairs) {
    __shared__ int bcnt[NBK], gbase[NBK], lcur[NBK];
    int t = threadIdx.x;
    if (t < NBK) { bcnt[t] = 0; lcur[t] = 0; }
    __syncthreads();
    int base = blockIdx.x * 4096;
#pragma unroll
    for (int i = 0; i < 16; ++i) {
        int e = base + t + i * 256;
        if (e < NE) atomicAdd(&bcnt[dst[e] >> 9], 1);
    }
    __syncthreads();
    if (t < NBK) gbase[t] = atomicAdd(&gcur[t * 16], bcnt[t]);
    __syncthreads();
#pragma unroll
    for (int i = 0; i < 16; ++i) {
        int e = base + t + i * 256;
        if (e < NE) {
            int d = dst[e];
            int b = d >> 9;
            int p = atomicAdd(&lcur[b], 1);
            pairs[gbase[b] + p] = ((unsigned)src[e] << 9) | (unsigned)(d & 511);
        }
    }
}

// ------- per bucket: node hist + scan -> row_ptr/inv_deg, then place edges -> csr -------
// csr stores src*256 (byte offset into bf16 h rows) to shorten the gather address path.
__global__ __launch_bounds__(512) void bucket_place(const unsigned* __restrict__ pairs,
                                                    const int* __restrict__ bbase,
                                                    int* __restrict__ row_ptr,
                                                    float* __restrict__ inv_deg,
                                                    int* __restrict__ csr) {
    __shared__ int hist[512], sc[512], cur[512];
    int b = blockIdx.x, t = threadIdx.x;
    hist[t] = 0;
    __syncthreads();
    int beg = bbase[b], end = bbase[b + 1];
    for (int i = beg + t; i < end; i += 512) atomicAdd(&hist[pairs[i] & 511u], 1);
    __syncthreads();
    int deg = hist[t];
    sc[t] = deg;
    __syncthreads();
    for (int off = 1; off < 512; off <<= 1) {
        int u = (t >= off) ? sc[t - off] : 0;
        __syncthreads();
        sc[t] += u;
        __syncthreads();
    }
    int ex = sc[t] - deg;
    int node = b * 512 + t;
    if (node < NN) {
        row_ptr[node] = beg + ex;
        inv_deg[node] = 1.0f / (float)max(deg, 1);
    }
    cur[t] = beg + ex;
    __syncthreads();
    for (int i = beg + t; i < end; i += 512) {
        unsigned p = pairs[i];
        int pos = atomicAdd(&cur[p & 511u], 1);
        csr[pos] = (int)(p >> 9) << 8;   // src * 256 bytes
    }
}

// ---------------- pack [W_self; W_neigh] (f32) into MFMA B-fragment bf16 layout ----------------
__global__ void pack_w(const float* __restrict__ Wself, const float* __restrict__ Wneigh,
                       unsigned short* __restrict__ wpack, int Ncols, int NF) {
    int idx = blockIdx.x * blockDim.x + threadIdx.x;
    int total = 8 * NF * 64 * 8;
    if (idx >= total) return;
    int j = idx & 7;
    int lane = (idx >> 3) & 63;
    int fid = idx >> 9;          // kstep*NF + nf
    int nf = fid % NF;
    int kstep = fid / NF;
    int k = kstep * 32 + (lane >> 4) * 8 + j;
    int n = nf * 16 + (lane & 15);
    float v = 0.f;
    if (n < Ncols) v = (k < 128) ? Wself[k * Ncols + n] : Wneigh[(k - 128) * Ncols + n];
    wpack[idx] = f2bf(v);
}

// ============ fused layer: aggregate (gather+mean) -> LDS -> dual-A MFMA GEMM ============
// block = 256 thr (4 waves) per 64-node tile. Phase 1: wave aggregates 16 nodes, bf16 rows
// into swizzled LDS. Phase 2: out = h@Wself + agg@Wneigh via 16x16x32 MFMA, A-agg from LDS.
template <int NF, bool LAST>
__global__ __launch_bounds__(256) void sage_layer(const unsigned* __restrict__ h32,
                                                  const int* __restrict__ csr,
                                                  const int* __restrict__ row_ptr,
                                                  const float* __restrict__ inv_deg,
                                                  const unsigned short* __restrict__ wpack,
                                                  unsigned short* __restrict__ hOut,
                                                  float* __restrict__ fOut) {
    __shared__ unsigned lds_agg[64 * 64];   // 64 rows x 64 dwords (128 bf16) = 16KB
    int lane = threadIdx.x & 63;
    int wave = threadIdx.x >> 6;
    int base = blockIdx.x * 64;
    const char* hb = (const char*)h32;
    unsigned lane4 = (unsigned)lane * 4;

    // ---- phase 1: aggregate 16 nodes per wave ----
    for (int i = 0; i < 16; ++i) {
        int node = base + wave * 16 + i;
        float a0 = 0.f, a1 = 0.f, b0 = 0.f, b1 = 0.f;
        float inv = 0.f;
        if (node < NN) {
            int beg = row_ptr[node], end = row_ptr[node + 1];
            inv = inv_deg[node];
            int e = beg;
            for (; e + 7 < end; e += 8) {
                unsigned o0 = (unsigned)csr[e]     + lane4;
                unsigned o1 = (unsigned)csr[e + 1] + lane4;
                unsigned o2 = (unsigned)csr[e + 2] + lane4;
                unsigned o3 = (unsigned)csr[e + 3] + lane4;
                unsigned o4 = (unsigned)csr[e + 4] + lane4;
                unsigned o5 = (unsigned)csr[e + 5] + lane4;
                unsigned o6 = (unsigned)csr[e + 6] + lane4;
                unsigned o7 = (unsigned)csr[e + 7] + lane4;
                unsigned v0 = *(const unsigned*)(hb + o0);
                unsigned v1 = *(const unsigned*)(hb + o1);
                unsigned v2 = *(const unsigned*)(hb + o2);
                unsigned v3 = *(const unsigned*)(hb + o3);
                unsigned v4 = *(const unsigned*)(hb + o4);
                unsigned v5 = *(const unsigned*)(hb + o5);
                unsigned v6 = *(const unsigned*)(hb + o6);
                unsigned v7 = *(const unsigned*)(hb + o7);
                a0 += bflo(v0) + bflo(v1) + bflo(v2) + bflo(v3);
                a1 += bfhi(v0) + bfhi(v1) + bfhi(v2) + bfhi(v3);
                b0 += bflo(v4) + bflo(v5) + bflo(v6) + bflo(v7);
                b1 += bfhi(v4) + bfhi(v5) + bfhi(v6) + bfhi(v7);
            }
            for (; e + 3 < end; e += 4) {
                unsigned v0 = *(const unsigned*)(hb + (unsigned)csr[e]     + lane4);
                unsigned v1 = *(const unsigned*)(hb + (unsigned)csr[e + 1] + lane4);
                unsigned v2 = *(const unsigned*)(hb + (unsigned)csr[e + 2] + lane4);
                unsigned v3 = *(const unsigned*)(hb + (unsigned)csr[e + 3] + lane4);
                a0 += bflo(v0) + bflo(v1) + bflo(v2) + bflo(v3);
                a1 += bfhi(v0) + bfhi(v1) + bfhi(v2) + bfhi(v3);
            }
            for (; e < end; ++e) {
                unsigned v = *(const unsigned*)(hb + (unsigned)csr[e] + lane4);
                a0 += bflo(v);
                a1 += bfhi(v);
            }
            a0 = (a0 + b0) * inv;
            a1 = (a1 + b1) * inv;
        }
        int r = wave * 16 + i;
        lds_agg[r * 64 + (lane ^ ((r & 7) << 2))] = ((unsigned)f2bf(a1) << 16) | f2bf(a0);
    }
    __syncthreads();

    // ---- phase 2: dual-A GEMM ----
    int aRow = base + wave * 16 + (lane & 15);
    int kgrp = (lane >> 4) * 8;
    int r = wave * 16 + (lane & 15);
    int swz = (r & 7) << 2;
    bool inb = (aRow < NN);
    const unsigned short* hA = (const unsigned short*)h32;

    f32x4 acc[NF];
#pragma unroll
    for (int f = 0; f < NF; ++f)
#pragma unroll
        for (int q = 0; q < 4; ++q) acc[f][q] = 0.f;

#pragma unroll
    for (int ks = 0; ks < 4; ++ks) {
        // self half (kstep = ks)
        bf16x8 aSelf;
        if (inb) {
            aSelf = *(const bf16x8*)(hA + (size_t)aRow * 128 + ks * 32 + kgrp);
        } else {
#pragma unroll
            for (int j = 0; j < 8; ++j) aSelf[j] = 0;
        }
#pragma unroll
        for (int nf = 0; nf < NF; ++nf) {
            bf16x8 b = *(const bf16x8*)(wpack + (((ks * NF + nf) * 64) + lane) * 8);
            acc[nf] = __builtin_amdgcn_mfma_f32_16x16x32_bf16(aSelf, b, acc[nf], 0, 0, 0);
        }
        // agg half (kstep = 4+ks), A from LDS
        int d0 = ks * 16 + (lane >> 4) * 4;
        bf16x8 aAgg = *(const bf16x8*)&lds_agg[r * 64 + (d0 ^ swz)];
#pragma unroll
        for (int nf = 0; nf < NF; ++nf) {
            bf16x8 b = *(const bf16x8*)(wpack + ((((4 + ks) * NF + nf) * 64) + lane) * 8);
            acc[nf] = __builtin_amdgcn_mfma_f32_16x16x32_bf16(aAgg, b, acc[nf], 0, 0, 0);
        }
    }

    int col0 = lane & 15;
    int rBase = base + wave * 16 + (lane >> 4) * 4;
#pragma unroll
    for (int nf = 0; nf < NF; ++nf) {
        int col = nf * 16 + col0;
        if (LAST) {
            if (col < 47) {
#pragma unroll
                for (int q = 0; q < 4; ++q) {
                    int row = rBase + q;
                    if (row < NN) fOut[(size_t)row * 47 + col] = acc[nf][q];
                }
            }
        } else {
#pragma unroll
            for (int q = 0; q < 4; ++q) {
                int row = rBase + q;
                if (row < NN) hOut[(size_t)row * 128 + col] = f2bf(fmaxf(acc[nf][q], 0.f));
            }
        }
    }
}

static inline size_t alignup(size_t x) { return (x + 255) & ~(size_t)255; }

extern "C" void kernel_launch(void* const* d_in, const int* in_sizes, int n_in,
                              void* d_out, int out_size, void* d_ws, size_t ws_size,
                              hipStream_t stream) {
    const float* x   = (const float*)d_in[0];
    const float* Ws0 = (const float*)d_in[1];
    const float* Wn0 = (const float*)d_in[2];
    const float* Ws1 = (const float*)d_in[3];
    const float* Wn1 = (const float*)d_in[4];
    const float* Ws2 = (const float*)d_in[5];
    const float* Wn2 = (const float*)d_in[6];
    const int* src   = (const int*)d_in[7];
    const int* dst   = (const int*)d_in[8];
    float* out = (float*)d_out;

    char* w = (char*)d_ws;
    size_t off = 0;
    int* row_ptr   = (int*)(w + off);   off += alignup((NN + 1) * 4);
    int* bhist     = (int*)(w + off);   off += alignup(NBK * 4);
    int* bbase     = (int*)(w + off);   off += alignup((NBK + 1) * 4);
    int* gcur      = (int*)(w + off);   off += alignup((size_t)NBK * 16 * 4);
    float* inv_deg = (float*)(w + off); off += alignup(NN * 4);
    int* csr       = (int*)(w + off);   off += alignup((size_t)NE * 4);
    unsigned* pairs = (unsigned*)(w + off); off += alignup((size_t)NE * 4);
    unsigned short* wp0 = (unsigned short*)(w + off); off += alignup(8 * 8 * 64 * 8 * 2);
    unsigned short* wp1 = (unsigned short*)(w + off); off += alignup(8 * 8 * 64 * 8 * 2);
    unsigned short* wp2 = (unsigned short*)(w + off); off += alignup(8 * 3 * 64 * 8 * 2);
    unsigned short* hA  = (unsigned short*)(w + off); off += alignup((size_t)NN * 128 * 2);
    unsigned short* hB  = (unsigned short*)(w + off); off += alignup((size_t)NN * 128 * 2);

    hipMemsetAsync(bhist, 0, NBK * 4, stream);

    cast_x<<<dim3((NN * 128 / 4 + 255) / 256), dim3(256), 0, stream>>>(x, hA, NN * 128);
    hist_buck<<<dim3((NE + 4095) / 4096), dim3(256), 0, stream>>>(dst, bhist);
    scan_buck<<<dim3(1), dim3(256), 0, stream>>>(bhist, bbase, gcur, row_ptr);
    sort_scatter<<<dim3((NE + 4095) / 4096), dim3(256), 0, stream>>>(src, dst, gcur, pairs);
    bucket_place<<<dim3(NBK), dim3(512), 0, stream>>>(pairs, bbase, row_ptr, inv_deg, csr);

    pack_w<<<dim3((8 * 8 * 64 * 8 + 255) / 256), dim3(256), 0, stream>>>(Ws0, Wn0, wp0, 128, 8);
    pack_w<<<dim3((8 * 8 * 64 * 8 + 255) / 256), dim3(256), 0, stream>>>(Ws1, Wn1, wp1, 128, 8);
    pack_w<<<dim3((8 * 3 * 64 * 8 + 255) / 256), dim3(256), 0, stream>>>(Ws2, Wn2, wp2, 47, 3);

    const int grid = (NN + 63) / 64;
    sage_layer<8, false><<<dim3(grid), dim3(256), 0, stream>>>(
        (const unsigned*)hA, csr, row_ptr, inv_deg, wp0, hB, nullptr);
    sage_layer<8, false><<<dim3(grid), dim3(256), 0, stream>>>(
        (const unsigned*)hB, csr, row_ptr, inv_deg, wp1, hA, nullptr);
    sage_layer<3, true><<<dim3(grid), dim3(256), 0, stream>>>(
        (const unsigned*)hA, csr, row_ptr, inv_deg, wp2, nullptr, out);
}

// Round 6
// 343.027 us; speedup vs baseline: 1.1316x; 1.1316x over previous
//
#include <hip/hip_runtime.h>
#include <hip/hip_bf16.h>

#define NN 100000
#define NE 1600000
#define NBK 196          // buckets of 512 nodes: ceil(100000/512)

typedef __attribute__((ext_vector_type(8))) short bf16x8;
typedef __attribute__((ext_vector_type(4))) float f32x4;

__device__ __forceinline__ unsigned short f2bf(float x) {
    unsigned u = __float_as_uint(x);
    return (unsigned short)((u + 0x7fffu + ((u >> 16) & 1u)) >> 16);
}
__device__ __forceinline__ float bflo(unsigned v) { return __uint_as_float(v << 16); }
__device__ __forceinline__ float bfhi(unsigned v) { return __uint_as_float(v & 0xffff0000u); }

#define ACC8(v) do { \
    acc[0] += bflo((v).x); acc[1] += bfhi((v).x); \
    acc[2] += bflo((v).y); acc[3] += bfhi((v).y); \
    acc[4] += bflo((v).z); acc[5] += bfhi((v).z); \
    acc[6] += bflo((v).w); acc[7] += bfhi((v).w); } while (0)

// ---------------- cast x (f32) -> bf16 ----------------
__global__ void cast_x(const float* __restrict__ x, unsigned short* __restrict__ h, int n) {
    int i = (blockIdx.x * blockDim.x + threadIdx.x) * 4;
    if (i >= n) return;
    float4 v = *(const float4*)(x + i);
    unsigned out0 = ((unsigned)f2bf(v.y) << 16) | f2bf(v.x);
    unsigned out1 = ((unsigned)f2bf(v.w) << 16) | f2bf(v.z);
    *(uint2*)(h + i) = make_uint2(out0, out1);
}

// ---------------- bucket histogram (196 buckets, LDS-first) ----------------
__global__ __launch_bounds__(256) void hist_buck(const int* __restrict__ dst, int* __restrict__ bhist) {
    __shared__ int h[NBK];
    int t = threadIdx.x;
    if (t < NBK) h[t] = 0;
    __syncthreads();
    int base = blockIdx.x * 4096;
#pragma unroll
    for (int i = 0; i < 16; ++i) {
        int e = base + t + i * 256;
        if (e < NE) atomicAdd(&h[dst[e] >> 9], 1);
    }
    __syncthreads();
    if (t < NBK && h[t]) atomicAdd(&bhist[t], h[t]);
}

// ------- scan buckets -> bbase (exclusive, bbase[NBK]=NE) + init gcur + row_ptr[NN] -------
__global__ void scan_buck(const int* __restrict__ bhist, int* __restrict__ bbase,
                          int* __restrict__ gcur, int* __restrict__ row_ptr) {
    __shared__ int s[256];
    int t = threadIdx.x;
    int v = (t < NBK) ? bhist[t] : 0;
    s[t] = v;
    __syncthreads();
    for (int off = 1; off < 256; off <<= 1) {
        int u = (t >= off) ? s[t - off] : 0;
        __syncthreads();
        s[t] += u;
        __syncthreads();
    }
    int ex = s[t] - v;
    if (t <= NBK) bbase[t] = ex;          // bbase[NBK] == NE
    if (t < NBK) gcur[t * 16] = ex;
    if (t == 0) row_ptr[NN] = NE;
}

// ------- block-local counting sort; contiguous runs per (block,bucket) -------
__global__ __launch_bounds__(256) void sort_scatter(const int* __restrict__ src,
                                                    const int* __restrict__ dst,
                                                    int* __restrict__ gcur,
                                                    unsigned* __restrict__ pairs) {
    __shared__ int bcnt[NBK], gbase[NBK], lcur[NBK];
    int t = threadIdx.x;
    if (t < NBK) { bcnt[t] = 0; lcur[t] = 0; }
    __syncthreads();
    int base = blockIdx.x * 4096;
#pragma unroll
    for (int i = 0; i < 16; ++i) {
        int e = base + t + i * 256;
        if (e < NE) atomicAdd(&bcnt[dst[e] >> 9], 1);
    }
    __syncthreads();
    if (t < NBK) gbase[t] = atomicAdd(&gcur[t * 16], bcnt[t]);
    __syncthreads();
#pragma unroll
    for (int i = 0; i < 16; ++i) {
        int e = base + t + i * 256;
        if (e < NE) {
            int d = dst[e];
            int b = d >> 9;
            int p = atomicAdd(&lcur[b], 1);
            pairs[gbase[b] + p] = ((unsigned)src[e] << 9) | (unsigned)(d & 511);
        }
    }
}

// ------- per bucket: node hist + scan -> row_ptr/inv_deg, then place edges -> csr -------
// csr stores src*256 (byte offset into 256B bf16 h rows).
__global__ __launch_bounds__(512) void bucket_place(const unsigned* __restrict__ pairs,
                                                    const int* __restrict__ bbase,
                                                    int* __restrict__ row_ptr,
                                                    float* __restrict__ inv_deg,
                                                    int* __restrict__ csr) {
    __shared__ int hist[512], sc[512], cur[512];
    int b = blockIdx.x, t = threadIdx.x;
    hist[t] = 0;
    __syncthreads();
    int beg = bbase[b], end = bbase[b + 1];
    for (int i = beg + t; i < end; i += 512) atomicAdd(&hist[pairs[i] & 511u], 1);
    __syncthreads();
    int deg = hist[t];
    sc[t] = deg;
    __syncthreads();
    for (int off = 1; off < 512; off <<= 1) {
        int u = (t >= off) ? sc[t - off] : 0;
        __syncthreads();
        sc[t] += u;
        __syncthreads();
    }
    int ex = sc[t] - deg;
    int node = b * 512 + t;
    if (node < NN) {
        row_ptr[node] = beg + ex;
        inv_deg[node] = 1.0f / (float)max(deg, 1);
    }
    cur[t] = beg + ex;
    __syncthreads();
    for (int i = beg + t; i < end; i += 512) {
        unsigned p = pairs[i];
        int pos = atomicAdd(&cur[p & 511u], 1);
        csr[pos] = (int)(p >> 9) << 8;   // src * 256 bytes
    }
}

// ---------------- pack [W_self; W_neigh] (f32) into MFMA B-fragment bf16 layout ----------------
__global__ void pack_w(const float* __restrict__ Wself, const float* __restrict__ Wneigh,
                       unsigned short* __restrict__ wpack, int Ncols, int NF) {
    int idx = blockIdx.x * blockDim.x + threadIdx.x;
    int total = 8 * NF * 64 * 8;
    if (idx >= total) return;
    int j = idx & 7;
    int lane = (idx >> 3) & 63;
    int fid = idx >> 9;          // kstep*NF + nf
    int nf = fid % NF;
    int kstep = fid / NF;
    int k = kstep * 32 + (lane >> 4) * 8 + j;
    int n = nf * 16 + (lane & 15);
    float v = 0.f;
    if (n < Ncols) v = (k < 128) ? Wself[k * Ncols + n] : Wneigh[(k - 128) * Ncols + n];
    wpack[idx] = f2bf(v);
}

// ---- aggregate: one node per wave; 16-lane groups, dwordx4 gathers, 4 edges/load ----
__global__ __launch_bounds__(256) void aggregate(const unsigned* __restrict__ h32,
                                                 const int* __restrict__ csr,
                                                 const int* __restrict__ row_ptr,
                                                 const float* __restrict__ inv_deg,
                                                 unsigned* __restrict__ agg32) {
    int lane = threadIdx.x & 63;
    int wave = threadIdx.x >> 6;
    int node = blockIdx.x * 4 + wave;
    if (node >= NN) return;
    int g = lane >> 4;          // edge subgroup 0..3
    unsigned l16 = (unsigned)(lane & 15) * 16;
    const char* hb = (const char*)h32;
    int beg = row_ptr[node], end = row_ptr[node + 1];
    float acc[8];
#pragma unroll
    for (int j = 0; j < 8; ++j) acc[j] = 0.f;

    int e = beg;
    for (; e + 15 < end; e += 16) {
        int c0 = csr[e + g];
        int c1 = csr[e + 4 + g];
        int c2 = csr[e + 8 + g];
        int c3 = csr[e + 12 + g];
        uint4 v0 = *(const uint4*)(hb + (unsigned)c0 + l16);
        uint4 v1 = *(const uint4*)(hb + (unsigned)c1 + l16);
        uint4 v2 = *(const uint4*)(hb + (unsigned)c2 + l16);
        uint4 v3 = *(const uint4*)(hb + (unsigned)c3 + l16);
        ACC8(v0); ACC8(v1); ACC8(v2); ACC8(v3);
    }
    for (; e + 3 < end; e += 4) {
        int c = csr[e + g];
        uint4 v = *(const uint4*)(hb + (unsigned)c + l16);
        ACC8(v);
    }
    int rem = end - e;
    if (g < rem) {
        int c = csr[e + g];
        uint4 v = *(const uint4*)(hb + (unsigned)c + l16);
        ACC8(v);
    }

#pragma unroll
    for (int j = 0; j < 8; ++j) {
        acc[j] += __shfl_xor(acc[j], 16, 64);
        acc[j] += __shfl_xor(acc[j], 32, 64);
    }
    float inv = inv_deg[node];
    if (lane < 16) {
        unsigned d0 = ((unsigned)f2bf(acc[1] * inv) << 16) | f2bf(acc[0] * inv);
        unsigned d1 = ((unsigned)f2bf(acc[3] * inv) << 16) | f2bf(acc[2] * inv);
        unsigned d2 = ((unsigned)f2bf(acc[5] * inv) << 16) | f2bf(acc[4] * inv);
        unsigned d3 = ((unsigned)f2bf(acc[7] * inv) << 16) | f2bf(acc[6] * inv);
        *(uint4*)((char*)agg32 + (size_t)node * 256 + l16) = make_uint4(d0, d1, d2, d3);
    }
}

// ---- agg_out (layer 2): gather 128B g-rows (h@Wn2, 64-bf16 padded), RMW-add into out ----
__global__ __launch_bounds__(256) void agg_out(const unsigned* __restrict__ g32,
                                               const int* __restrict__ csr,
                                               const int* __restrict__ row_ptr,
                                               const float* __restrict__ inv_deg,
                                               float* __restrict__ out) {
    int lane = threadIdx.x & 63;
    int wave = threadIdx.x >> 6;
    int node = blockIdx.x * 4 + wave;
    if (node >= NN) return;
    int g = lane >> 3;          // edge subgroup 0..7
    int l = lane & 7;
    unsigned l16 = (unsigned)l * 16;
    const char* gb = (const char*)g32;
    int beg = row_ptr[node], end = row_ptr[node + 1];
    float acc[8];
#pragma unroll
    for (int j = 0; j < 8; ++j) acc[j] = 0.f;

    int e = beg;
    for (; e + 15 < end; e += 16) {
        int c0 = csr[e + g];
        int c1 = csr[e + 8 + g];
        uint4 v0 = *(const uint4*)(gb + ((unsigned)c0 >> 1) + l16);
        uint4 v1 = *(const uint4*)(gb + ((unsigned)c1 >> 1) + l16);
        ACC8(v0); ACC8(v1);
    }
    for (; e + 7 < end; e += 8) {
        int c = csr[e + g];
        uint4 v = *(const uint4*)(gb + ((unsigned)c >> 1) + l16);
        ACC8(v);
    }
    int rem = end - e;
    if (g < rem) {
        int c = csr[e + g];
        uint4 v = *(const uint4*)(gb + ((unsigned)c >> 1) + l16);
        ACC8(v);
    }

#pragma unroll
    for (int j = 0; j < 8; ++j) {
        acc[j] += __shfl_xor(acc[j], 8, 64);
        acc[j] += __shfl_xor(acc[j], 16, 64);
        acc[j] += __shfl_xor(acc[j], 32, 64);
    }
    float inv = inv_deg[node];
    if (lane < 8) {
        float* orow = out + (size_t)node * 47;
#pragma unroll
        for (int j = 0; j < 8; ++j) {
            int f = l * 8 + j;
            if (f < 47) orow[f] += acc[j] * inv;
        }
    }
}

// ---------------- fused GEMM (layers 0,1): out = relu(h@Wself + agg@Wneigh) ----------------
template <int NF>
__global__ __launch_bounds__(256) void gemm_k(const unsigned short* __restrict__ hA,
                                              const unsigned short* __restrict__ hAgg,
                                              const unsigned short* __restrict__ wpack,
                                              unsigned short* __restrict__ hOut) {
    int lane = threadIdx.x & 63;
    int wave = threadIdx.x >> 6;
    int aRow = blockIdx.x * 64 + wave * 16 + (lane & 15);
    int kgrp = (lane >> 4) * 8;

    f32x4 acc[NF];
#pragma unroll
    for (int f = 0; f < NF; ++f)
#pragma unroll
        for (int q = 0; q < 4; ++q) acc[f][q] = 0.f;

    bool inb = (aRow < NN);
#pragma unroll
    for (int half = 0; half < 2; ++half) {
        const unsigned short* A = half ? hAgg : hA;
#pragma unroll
        for (int ks = 0; ks < 4; ++ks) {
            bf16x8 afrag;
            if (inb) {
                afrag = *(const bf16x8*)(A + (size_t)aRow * 128 + ks * 32 + kgrp);
            } else {
#pragma unroll
                for (int j = 0; j < 8; ++j) afrag[j] = 0;
            }
            int kstep = half * 4 + ks;
#pragma unroll
            for (int nf = 0; nf < NF; ++nf) {
                bf16x8 b = *(const bf16x8*)(wpack + (((kstep * NF + nf) * 64) + lane) * 8);
                acc[nf] = __builtin_amdgcn_mfma_f32_16x16x32_bf16(afrag, b, acc[nf], 0, 0, 0);
            }
        }
    }

    int col0 = lane & 15;
    int rBase = blockIdx.x * 64 + wave * 16 + (lane >> 4) * 4;
#pragma unroll
    for (int nf = 0; nf < NF; ++nf) {
        int col = nf * 16 + col0;
#pragma unroll
        for (int q = 0; q < 4; ++q) {
            int row = rBase + q;
            if (row < NN) hOut[(size_t)row * 128 + col] = f2bf(fmaxf(acc[nf][q], 0.f));
        }
    }
}

// ---- gemm_last (layer 2): out = h@Ws2 (f32, cols<47); g64 = h@Wn2 (bf16, 64-padded) ----
__global__ __launch_bounds__(256) void gemm_last(const unsigned short* __restrict__ hA,
                                                 const unsigned short* __restrict__ wpack,
                                                 unsigned short* __restrict__ g64,
                                                 float* __restrict__ out) {
    int lane = threadIdx.x & 63;
    int wave = threadIdx.x >> 6;
    int aRow = blockIdx.x * 64 + wave * 16 + (lane & 15);
    int kgrp = (lane >> 4) * 8;

    f32x4 accS[3], accG[3];
#pragma unroll
    for (int f = 0; f < 3; ++f)
#pragma unroll
        for (int q = 0; q < 4; ++q) { accS[f][q] = 0.f; accG[f][q] = 0.f; }

    bool inb = (aRow < NN);
#pragma unroll
    for (int ks = 0; ks < 4; ++ks) {
        bf16x8 afrag;
        if (inb) {
            afrag = *(const bf16x8*)(hA + (size_t)aRow * 128 + ks * 32 + kgrp);
        } else {
#pragma unroll
            for (int j = 0; j < 8; ++j) afrag[j] = 0;
        }
#pragma unroll
        for (int nf = 0; nf < 3; ++nf) {
            bf16x8 bS = *(const bf16x8*)(wpack + (((ks * 3 + nf) * 64) + lane) * 8);
            accS[nf] = __builtin_amdgcn_mfma_f32_16x16x32_bf16(afrag, bS, accS[nf], 0, 0, 0);
            bf16x8 bG = *(const bf16x8*)(wpack + ((((4 + ks) * 3 + nf) * 64) + lane) * 8);
            accG[nf] = __builtin_amdgcn_mfma_f32_16x16x32_bf16(afrag, bG, accG[nf], 0, 0, 0);
        }
    }

    int col0 = lane & 15;
    int rBase = blockIdx.x * 64 + wave * 16 + (lane >> 4) * 4;
#pragma unroll
    for (int nf = 0; nf < 3; ++nf) {
        int col = nf * 16 + col0;
#pragma unroll
        for (int q = 0; q < 4; ++q) {
            int row = rBase + q;
            if (row < NN) {
                if (col < 47) out[(size_t)row * 47 + col] = accS[nf][q];
                g64[(size_t)row * 64 + col] = f2bf(accG[nf][q]);   // col <= 47; Wn2 col47 packs as 0
            }
        }
    }
}

static inline size_t alignup(size_t x) { return (x + 255) & ~(size_t)255; }

extern "C" void kernel_launch(void* const* d_in, const int* in_sizes, int n_in,
                              void* d_out, int out_size, void* d_ws, size_t ws_size,
                              hipStream_t stream) {
    const float* x   = (const float*)d_in[0];
    const float* Ws0 = (const float*)d_in[1];
    const float* Wn0 = (const float*)d_in[2];
    const float* Ws1 = (const float*)d_in[3];
    const float* Wn1 = (const float*)d_in[4];
    const float* Ws2 = (const float*)d_in[5];
    const float* Wn2 = (const float*)d_in[6];
    const int* src   = (const int*)d_in[7];
    const int* dst   = (const int*)d_in[8];
    float* out = (float*)d_out;

    char* w = (char*)d_ws;
    size_t off = 0;
    int* row_ptr   = (int*)(w + off);   off += alignup((NN + 1) * 4);
    int* bhist     = (int*)(w + off);   off += alignup(NBK * 4);
    int* bbase     = (int*)(w + off);   off += alignup((NBK + 1) * 4);
    int* gcur      = (int*)(w + off);   off += alignup((size_t)NBK * 16 * 4);
    float* inv_deg = (float*)(w + off); off += alignup(NN * 4);
    int* csr       = (int*)(w + off);   off += alignup((size_t)NE * 4);
    unsigned* pairs = (unsigned*)(w + off); off += alignup((size_t)NE * 4);
    unsigned short* wp0 = (unsigned short*)(w + off); off += alignup(8 * 8 * 64 * 8 * 2);
    unsigned short* wp1 = (unsigned short*)(w + off); off += alignup(8 * 8 * 64 * 8 * 2);
    unsigned short* wp2 = (unsigned short*)(w + off); off += alignup(8 * 3 * 64 * 8 * 2);
    unsigned short* hA  = (unsigned short*)(w + off); off += alignup((size_t)NN * 128 * 2);
    unsigned short* hB  = (unsigned short*)(w + off); off += alignup((size_t)NN * 128 * 2);
    unsigned short* agg = (unsigned short*)(w + off); off += alignup((size_t)NN * 128 * 2);
    unsigned short* g64 = agg;   // alias: layer-2 transformed rows (12.8MB) reuse agg buffer

    hipMemsetAsync(bhist, 0, NBK * 4, stream);

    cast_x<<<dim3((NN * 128 / 4 + 255) / 256), dim3(256), 0, stream>>>(x, hA, NN * 128);
    hist_buck<<<dim3((NE + 4095) / 4096), dim3(256), 0, stream>>>(dst, bhist);
    scan_buck<<<dim3(1), dim3(256), 0, stream>>>(bhist, bbase, gcur, row_ptr);
    sort_scatter<<<dim3((NE + 4095) / 4096), dim3(256), 0, stream>>>(src, dst, gcur, pairs);
    bucket_place<<<dim3(NBK), dim3(512), 0, stream>>>(pairs, bbase, row_ptr, inv_deg, csr);

    pack_w<<<dim3((8 * 8 * 64 * 8 + 255) / 256), dim3(256), 0, stream>>>(Ws0, Wn0, wp0, 128, 8);
    pack_w<<<dim3((8 * 8 * 64 * 8 + 255) / 256), dim3(256), 0, stream>>>(Ws1, Wn1, wp1, 128, 8);
    pack_w<<<dim3((8 * 3 * 64 * 8 + 255) / 256), dim3(256), 0, stream>>>(Ws2, Wn2, wp2, 47, 3);

    const int aggGrid  = (NN + 3) / 4;
    const int gemmGrid = (NN + 63) / 64;

    // layer 0
    aggregate<<<dim3(aggGrid), dim3(256), 0, stream>>>((const unsigned*)hA, csr, row_ptr, inv_deg, (unsigned*)agg);
    gemm_k<8><<<dim3(gemmGrid), dim3(256), 0, stream>>>(hA, agg, wp0, hB);
    // layer 1
    aggregate<<<dim3(aggGrid), dim3(256), 0, stream>>>((const unsigned*)hB, csr, row_ptr, inv_deg, (unsigned*)agg);
    gemm_k<8><<<dim3(gemmGrid), dim3(256), 0, stream>>>(hB, agg, wp1, hA);
    // layer 2: transform-first, then aggregate 128B rows and RMW into out
    gemm_last<<<dim3(gemmGrid), dim3(256), 0, stream>>>(hA, wp2, g64, out);
    agg_out<<<dim3(aggGrid), dim3(256), 0, stream>>>((const unsigned*)g64, csr, row_ptr, inv_deg, out);
}